// Round 5
// baseline (2104.341 us; speedup 1.0000x reference)
//
#include <hip/hip_runtime.h>

// GLIFR RNN (B=64, T=200, IN=512, HID=1024, OUT=512), fp32 in/out, bf16 MFMA.
//
// Round 5: round-4's fused chain, but with a MANUAL device-scope grid barrier
// instead of hipLaunchCooperativeKernel (whose launch silently failed -> F
// stayed poison). Co-residency for 320 blocks is guaranteed:
// __launch_bounds__(256,2) caps VGPR at 256 (>=2 blocks/CU), LDS 32 KB/block,
// so capacity >= 512 blocks and the counter barrier cannot deadlock.
//
// Chain: for c = 1..9 { syn[c] = [xb_c | F_{c-1}] @ [WinT|WlatT]^T ; bar ;
// GLIFR step x20 ; bar }.  GLIFR state lives in registers across chunks.
//
// Workspace (~97 MB):
//   syn   fp32 [T,B,H]    @ 0          (52428800 B)
//   F     bf16 [T,B,H]    @ 53477376   (26214400 B)
//   WinT  bf16 [H,IN]     @ 79691776   (1048576 B)
//   WlatT bf16 [H,H]      @ 80740352   (2097152 B)
//   WoutB bf16 [OUT,H]    @ 82837504   (1048576 B)
//   xb    bf16 [12800,512]@ 83886080   (13107200 B)
//   bar   u32 x64         @ 100663296  (256 B)  cnt @0, gen @32

typedef float f32x4 __attribute__((ext_vector_type(4)));
typedef __bf16 bf16x8 __attribute__((ext_vector_type(8)));
typedef unsigned short ushortx8 __attribute__((ext_vector_type(8)));
typedef unsigned short ushortx4 __attribute__((ext_vector_type(4)));

__device__ __forceinline__ unsigned short f2b(float f) {
    unsigned int u = __float_as_uint(f);
    unsigned int r = u + 0x7FFFu + ((u >> 16) & 1u);   // RNE
    return (unsigned short)(r >> 16);
}
__device__ __forceinline__ float sigmoidf(float x) {
    return 1.0f / (1.0f + __expf(-x));
}

// async global->LDS, 16 B per lane; LDS dest is wave-uniform base + lane*16
__device__ __forceinline__ void gl_lds16(const unsigned short* g, unsigned short* l) {
    __builtin_amdgcn_global_load_lds(
        (const __attribute__((address_space(1))) void*)g,
        (__attribute__((address_space(3))) void*)l, 16, 0, 0);
}

// Manual grid barrier: counter + generation, agent(device)-scope atomics.
// Safe: all blocks provably co-resident (see header comment).
__device__ __forceinline__ void grid_bar(unsigned* cnt, unsigned* gen, unsigned nb) {
    __threadfence();                       // release this thread's writes
    __syncthreads();
    if (threadIdx.x == 0) {
        unsigned g = __hip_atomic_load(gen, __ATOMIC_RELAXED, __HIP_MEMORY_SCOPE_AGENT);
        if (__hip_atomic_fetch_add(cnt, 1u, __ATOMIC_ACQ_REL,
                                   __HIP_MEMORY_SCOPE_AGENT) == nb - 1u) {
            __hip_atomic_store(cnt, 0u, __ATOMIC_RELAXED, __HIP_MEMORY_SCOPE_AGENT);
            __hip_atomic_fetch_add(gen, 1u, __ATOMIC_RELEASE, __HIP_MEMORY_SCOPE_AGENT);
        } else {
            while (__hip_atomic_load(gen, __ATOMIC_ACQUIRE,
                                     __HIP_MEMORY_SCOPE_AGENT) == g)
                __builtin_amdgcn_s_sleep(2);
        }
    }
    __syncthreads();
    __threadfence();                       // acquire for all threads
}

__global__ void init_barrier(unsigned* p) {
    if (threadIdx.x < 64) p[threadIdx.x] = 0u;
}

// ---------------------------------------------------------------------------
// fp32 [R,C] -> bf16 transposed [C,R]
// ---------------------------------------------------------------------------
__global__ __launch_bounds__(256) void transpose_f32_to_bf16(
    const float* __restrict__ in, unsigned short* __restrict__ out,
    int R, int C)
{
    __shared__ unsigned short t[64][65];
    int bx = blockIdx.x * 64, by = blockIdx.y * 64;
    int tx = threadIdx.x & 63, ty = threadIdx.x >> 6;
    for (int r = ty; r < 64; r += 4)
        t[r][tx] = f2b(in[(size_t)(by + r) * C + bx + tx]);
    __syncthreads();
    for (int r = ty; r < 64; r += 4)
        out[(size_t)(bx + r) * R + by + tx] = t[tx][r];
}

// fp32 -> bf16 elementwise (n multiple of 1024)
__global__ __launch_bounds__(256) void convert_f32_to_bf16(
    const float* __restrict__ in, unsigned short* __restrict__ out)
{
    int i = (blockIdx.x * 256 + threadIdx.x) * 4;
    f32x4 v = *(const f32x4*)(in + i);
    ushortx4 o;
    o[0] = f2b(v[0]); o[1] = f2b(v[1]); o[2] = f2b(v[2]); o[3] = f2b(v[3]);
    *(ushortx4*)(out + i) = o;
}

// x [B=64,T=200,IN=512] fp32 -> xb [m=t*64+b][512] bf16
__global__ __launch_bounds__(256) void convert_x(
    const float* __restrict__ x, unsigned short* __restrict__ xb)
{
    size_t i8 = (size_t)(blockIdx.x * 256 + threadIdx.x) * 8;   // grid 3200
    int m = (int)(i8 >> 9), k = (int)(i8 & 511);
    int b = m & 63, t = m >> 6;
    const float* src = x + ((size_t)b * 200 + t) * 512 + k;
    f32x4 v0 = *(const f32x4*)src;
    f32x4 v1 = *(const f32x4*)(src + 4);
    ushortx8 o;
    o[0] = f2b(v0[0]); o[1] = f2b(v0[1]); o[2] = f2b(v0[2]); o[3] = f2b(v0[3]);
    o[4] = f2b(v1[0]); o[5] = f2b(v1[1]); o[6] = f2b(v1[2]); o[7] = f2b(v1[3]);
    *(ushortx8*)(xb + i8) = o;
}

// ---------------------------------------------------------------------------
// NT GEMM (proj chunk-0 & readout). A,Bt bf16 row-major K-contig.
// LDS swizzle: 16B chunk c of row r at slot (c ^ (r&7)).
// MODE 0: zero init, fp32 out identity rows.            (proj chunk 0)
// MODE 2: zero init, +bias, fp32 out remapped [B,T,OUT] (readout)
// ---------------------------------------------------------------------------
template<int BM, int BN, int MODE>
__global__ __launch_bounds__(256) void gemm_nt(
    const unsigned short* __restrict__ A,
    const unsigned short* __restrict__ Bt,
    float* __restrict__ outf,
    const float* __restrict__ bias,
    int M, int N, int K)
{
    constexpr int WM = BM / 2, WN = BN / 2;
    constexpr int TM = WM / 16, TN = WN / 16;

    __shared__ unsigned short Asm[BM * 64];
    __shared__ unsigned short Bsm[BN * 64];

    const int tid  = threadIdx.x;
    const int wave = tid >> 6, lane = tid & 63;
    const int m16  = lane & 15, quad = lane >> 4;
    const int bm0  = blockIdx.y * BM, bn0 = blockIdx.x * BN;
    const int wr   = (wave >> 1) * WM, wc = (wave & 1) * WN;
    const int sr   = lane >> 3, sc = lane & 7;

    f32x4 acc[TM][TN];
#pragma unroll
    for (int i = 0; i < TM; i++)
#pragma unroll
        for (int j = 0; j < TN; j++)
            acc[i][j] = (f32x4){0.f, 0.f, 0.f, 0.f};

    for (int k0 = 0; k0 < K; k0 += 64) {
#pragma unroll
        for (int g = wave; g < BM / 8; g += 4) {
            int r = g * 8 + sr;
            int c = sc ^ (r & 7);
            gl_lds16(A + (size_t)(bm0 + r) * K + k0 + c * 8, Asm + g * 512);
        }
#pragma unroll
        for (int g = wave; g < BN / 8; g += 4) {
            int r = g * 8 + sr;
            int c = sc ^ (r & 7);
            gl_lds16(Bt + (size_t)(bn0 + r) * K + k0 + c * 8, Bsm + g * 512);
        }
        __syncthreads();

        ushortx8 af[2][TM], bfr[2][TN];
#pragma unroll
        for (int kh = 0; kh < 2; kh++) {
#pragma unroll
            for (int i = 0; i < TM; i++) {
                int ra = wr + i * 16 + m16;
                af[kh][i] = *(const ushortx8*)(
                    Asm + ra * 64 + (((kh * 4 + quad) ^ (ra & 7)) * 8));
            }
#pragma unroll
            for (int j = 0; j < TN; j++) {
                int rb = wc + j * 16 + m16;
                bfr[kh][j] = *(const ushortx8*)(
                    Bsm + rb * 64 + (((kh * 4 + quad) ^ (rb & 7)) * 8));
            }
        }
#pragma unroll
        for (int i = 0; i < TM; i++)
#pragma unroll
            for (int j = 0; j < TN; j++) {
                acc[i][j] = __builtin_amdgcn_mfma_f32_16x16x32_bf16(
                    __builtin_bit_cast(bf16x8, af[0][i]),
                    __builtin_bit_cast(bf16x8, bfr[0][j]),
                    acc[i][j], 0, 0, 0);
                acc[i][j] = __builtin_amdgcn_mfma_f32_16x16x32_bf16(
                    __builtin_bit_cast(bf16x8, af[1][i]),
                    __builtin_bit_cast(bf16x8, bfr[1][j]),
                    acc[i][j], 0, 0, 0);
            }
        __syncthreads();
    }

    // epilogue; C/D layout: col = lane&15, row = quad*4 + reg  (m89-verified)
#pragma unroll
    for (int i = 0; i < TM; i++)
#pragma unroll
        for (int j = 0; j < TN; j++) {
            int col = bn0 + wc + j * 16 + m16;
            float bv = (MODE == 2) ? bias[col] : 0.f;
#pragma unroll
            for (int v = 0; v < 4; v++) {
                int row = bm0 + wr + i * 16 + quad * 4 + v;
                if (MODE == 2) {
                    size_t o = (size_t)((row & 63) * 200 + (row >> 6)) * N + col;
                    outf[o] = acc[i][j][v] + bv;
                } else {
                    outf[(size_t)row * N + col] = acc[i][j][v];
                }
            }
        }
}

// ---------------------------------------------------------------------------
// Fused chain, manual grid barrier. 320 blocks x 256 threads.
// Block b: GEMM tile s = b>>4 (timestep within chunk), n-tile = b&15.
// Blocks 0..255 also own 256 (b,h) step elements, state in registers.
// ---------------------------------------------------------------------------
#define NBLK 320u
__global__ __launch_bounds__(256, 2) void chain_fused(
    float* __restrict__ syn,
    unsigned short* __restrict__ F,
    const unsigned short* __restrict__ xb,
    const unsigned short* __restrict__ WinT,
    const unsigned short* __restrict__ WlatT,
    const float* __restrict__ thresh,
    const float* __restrict__ t_km,
    const float* __restrict__ t_ak,
    const float* __restrict__ amp,
    const float* __restrict__ t_ar,
    unsigned* __restrict__ bar)
{
    unsigned* cnt = bar;
    unsigned* gen = bar + 32;

    const int tid  = threadIdx.x;
    const int blk  = blockIdx.x;
    const int wave = tid >> 6, lane = tid & 63;
    const int m16  = lane & 15, quad = lane >> 4;
    const int wr   = (wave >> 1) * 32, wc = (wave & 1) * 32;
    const int sr   = lane >> 3, sc = lane & 7;
    const int m0   = (blk >> 4) * 64;     // chunk-local row base (timestep s)
    const int n0   = (blk & 15) * 64;

    __shared__ unsigned short Asm[64 * 64];
    __shared__ unsigned short Bsm[64 * 64];

    // ---- per-thread GLIFR state (blocks 0..255 own 256 elements each) ----
    const int BH = 65536;
    const int sidx = blk * 256 + tid;      // b*1024 + h  (valid when blk<256)
    const bool isStep = blk < 256;
    const int h = sidx & 1023;
    const float th  = thresh[h];
    const float sm  = sigmoidf(t_km[h]);
    const float rm  = 0.1f * sm, om = 1.f - sm;
    const float sa0 = sigmoidf(t_ak[h]),  sa1 = sigmoidf(t_ak[1024 + h]);
    const float am0 = amp[h],             am1 = amp[1024 + h];
    const float r0  = 1.f - 2.f * sigmoidf(t_ar[h]);
    const float r1  = 1.f - 2.f * sigmoidf(t_ar[1024 + h]);
    float volt = 0.f, a0 = 0.f, a1 = 0.f, fir = 0.f;

    auto step20 = [&](int t0) {
#pragma unroll
        for (int s = 0; s < 20; s++) {
            float sv  = syn[(size_t)(t0 + s) * BH + sidx];
            float na0 = (am0 + r0 * a0) * fir * sa0 + (1.f - sa0) * a0;
            float na1 = (am1 + r1 * a1) * fir * sa1 + (1.f - sa1) * a1;
            volt = rm * (sv + na0 + na1) + om * volt;
            fir  = sigmoidf(volt - th);
            F[(size_t)(t0 + s) * BH + sidx] = f2b(fir);
            a0 = na0; a1 = na1;
        }
    };

    if (isStep) step20(0);          // chunk 0: syn = xproj (precomputed)
    grid_bar(cnt, gen, NBLK);       // F chunk 0 visible

    const size_t CHUNK = 20u * 64u * 1024u;

    for (int c = 1; c < 10; c++) {
        f32x4 acc[2][2];
#pragma unroll
        for (int i = 0; i < 2; i++)
#pragma unroll
            for (int j = 0; j < 2; j++)
                acc[i][j] = (f32x4){0.f, 0.f, 0.f, 0.f};

        auto kloop = [&](const unsigned short* Ab, const unsigned short* Bb,
                         int ldk, int nk) {
            for (int kk = 0; kk < nk; kk++) {
                int k0 = kk * 64;
#pragma unroll
                for (int g = wave; g < 8; g += 4) {
                    int r = g * 8 + sr;
                    int cc = sc ^ (r & 7);
                    gl_lds16(Ab + (size_t)r * ldk + k0 + cc * 8, Asm + g * 512);
                }
#pragma unroll
                for (int g = wave; g < 8; g += 4) {
                    int r = g * 8 + sr;
                    int cc = sc ^ (r & 7);
                    gl_lds16(Bb + (size_t)r * ldk + k0 + cc * 8, Bsm + g * 512);
                }
                __syncthreads();

                ushortx8 af[2][2], bfr[2][2];
#pragma unroll
                for (int kh = 0; kh < 2; kh++) {
#pragma unroll
                    for (int i = 0; i < 2; i++) {
                        int ra = wr + i * 16 + m16;
                        af[kh][i] = *(const ushortx8*)(
                            Asm + ra * 64 + (((kh * 4 + quad) ^ (ra & 7)) * 8));
                    }
#pragma unroll
                    for (int j = 0; j < 2; j++) {
                        int rb = wc + j * 16 + m16;
                        bfr[kh][j] = *(const ushortx8*)(
                            Bsm + rb * 64 + (((kh * 4 + quad) ^ (rb & 7)) * 8));
                    }
                }
#pragma unroll
                for (int i = 0; i < 2; i++)
#pragma unroll
                    for (int j = 0; j < 2; j++) {
                        acc[i][j] = __builtin_amdgcn_mfma_f32_16x16x32_bf16(
                            __builtin_bit_cast(bf16x8, af[0][i]),
                            __builtin_bit_cast(bf16x8, bfr[0][j]),
                            acc[i][j], 0, 0, 0);
                        acc[i][j] = __builtin_amdgcn_mfma_f32_16x16x32_bf16(
                            __builtin_bit_cast(bf16x8, af[1][i]),
                            __builtin_bit_cast(bf16x8, bfr[1][j]),
                            acc[i][j], 0, 0, 0);
                    }
                __syncthreads();
            }
        };

        // concatenated K: input projection (K=512) + lateral (K=1024)
        kloop(xb + (size_t)(c * 1280 + m0) * 512,
              WinT + (size_t)n0 * 512, 512, 8);
        kloop(F + (size_t)(c - 1) * CHUNK + (size_t)m0 * 1024,
              WlatT + (size_t)n0 * 1024, 1024, 16);

        // epilogue: direct store of syn chunk c
#pragma unroll
        for (int i = 0; i < 2; i++)
#pragma unroll
            for (int j = 0; j < 2; j++) {
                int col = n0 + wc + j * 16 + m16;
#pragma unroll
                for (int v = 0; v < 4; v++) {
                    int row = m0 + wr + i * 16 + quad * 4 + v;
                    syn[(size_t)c * CHUNK + (size_t)row * 1024 + col] =
                        acc[i][j][v];
                }
            }

        grid_bar(cnt, gen, NBLK);    // syn chunk c visible
        if (isStep) step20(c * 20);
        grid_bar(cnt, gen, NBLK);    // F chunk c visible
    }
}

// ---------------------------------------------------------------------------
extern "C" void kernel_launch(void* const* d_in, const int* in_sizes, int n_in,
                              void* d_out, int out_size, void* d_ws, size_t ws_size,
                              hipStream_t stream)
{
    const float* x      = (const float*)d_in[0];  // [64,200,512]
    const float* W_in   = (const float*)d_in[1];  // [512,1024]
    const float* W_lat  = (const float*)d_in[2];  // [1024,1024]
    const float* thresh = (const float*)d_in[3];  // [1,1024]
    const float* t_km   = (const float*)d_in[4];  // [1,1024]
    const float* t_ak   = (const float*)d_in[5];  // [2,1,1024]
    const float* amp    = (const float*)d_in[6];  // [2,1,1024]
    const float* t_ar   = (const float*)d_in[7];  // [2,1,1024]
    const float* W_out  = (const float*)d_in[8];  // [512,1024] (n,k) already
    const float* b_out  = (const float*)d_in[9];  // [512]
    float* out = (float*)d_out;                   // [64,200,512]

    char* ws = (char*)d_ws;
    float*          syn   = (float*)ws;
    unsigned short* F     = (unsigned short*)(ws + 53477376);
    unsigned short* WinT  = (unsigned short*)(ws + 79691776);
    unsigned short* WlatT = (unsigned short*)(ws + 80740352);
    unsigned short* WoutB = (unsigned short*)(ws + 82837504);
    unsigned short* xb    = (unsigned short*)(ws + 83886080);
    unsigned*       bar   = (unsigned*)(ws + 100663296);

    // Prep: zero barrier (ws is poisoned each launch); weights->bf16; x->bf16.
    init_barrier<<<1, 64, 0, stream>>>(bar);
    transpose_f32_to_bf16<<<dim3(16, 8),  256, 0, stream>>>(W_in,  WinT,  512,  1024);
    transpose_f32_to_bf16<<<dim3(16, 16), 256, 0, stream>>>(W_lat, WlatT, 1024, 1024);
    convert_f32_to_bf16<<<512, 256, 0, stream>>>(W_out, WoutB);
    convert_x<<<3200, 256, 0, stream>>>(x, xb);

    // proj for chunk 0 only: syn[0:1280] = xb[0:1280] @ WinT^T
    gemm_nt<64, 64, 0><<<dim3(16, 20), 256, 0, stream>>>(
        xb, WinT, syn, nullptr, 1280, 1024, 512);

    // fused chain: chunks 0..9 step + 1..9 concat-K GEMM, manual grid barrier
    chain_fused<<<NBLK, 256, 0, stream>>>(
        syn, F, xb, WinT, WlatT, thresh, t_km, t_ak, amp, t_ar, bar);

    // readout: out[b,t,:] = F[t,b,:] @ W_out^T + b_out
    gemm_nt<128, 128, 2><<<dim3(4, 100), 256, 0, stream>>>(
        F, WoutB, out, b_out, 12800, 512, 1024);
}

// Round 6
// 365.043 us; speedup vs baseline: 5.7646x; 5.7646x over previous
//
#include <hip/hip_runtime.h>

// GLIFR RNN (B=64, T=200, IN=512, HID=1024, OUT=512), fp32 in/out, bf16 MFMA.
//
// Round 6: block-local fusion. Rows reordered to m = b*20+s per chunk, so
// block (btile,ntile) owns an 80x64 tile = (4 b x 20 s) x 64 h. Its GEMM
// (concat-K: [xb_c | F_{c-1}] @ [WinT|WlatT], K=512(+1024)) lands in LDS;
// the SAME block runs the 20-step GLIFR recurrence from LDS with state in
// registers across all 10 chunks. syn never touches HBM. Cross-block dep
// (F) is a monotonic flag per (chunk,btile): release fetch_add by tid0 only
// (round 5's all-thread __threadfence storm flushed L2 ~50k times -> 2 ms).
// Readout (F @ W_out^T + b) folded into the same kernel after flag[9].
//
// Workspace (~44 MB):
//   F     bf16 [10][1280][1024] @ 0          (26214400 B)  rows b*20+s
//   xb    bf16 [10][1280][512]  @ 26214400   (13107200 B)  rows b*20+s
//   WinT  bf16 [1024][512]      @ 39321600   (1048576 B)
//   WlatT bf16 [1024][1024]     @ 40370176   (2097152 B)
//   WoutB bf16 [512][1024]      @ 42467328   (1048576 B)
//   flags u32  [10][16]+pad     @ 43515904   (1024 B)

typedef float f32x4 __attribute__((ext_vector_type(4)));
typedef __bf16 bf16x8 __attribute__((ext_vector_type(8)));
typedef unsigned short ushortx8 __attribute__((ext_vector_type(8)));
typedef unsigned short ushortx4 __attribute__((ext_vector_type(4)));

__device__ __forceinline__ unsigned short f2b(float f) {
    unsigned int u = __float_as_uint(f);
    unsigned int r = u + 0x7FFFu + ((u >> 16) & 1u);   // RNE
    return (unsigned short)(r >> 16);
}
__device__ __forceinline__ float sigmoidf(float x) {
    return 1.0f / (1.0f + __expf(-x));
}

// async global->LDS, 16 B per lane; LDS dest is wave-uniform base + lane*16
__device__ __forceinline__ void gl_lds16(const unsigned short* g, unsigned short* l) {
    __builtin_amdgcn_global_load_lds(
        (const __attribute__((address_space(1))) void*)g,
        (__attribute__((address_space(3))) void*)l, 16, 0, 0);
}

// ---------------------------------------------------------------------------
// One prep kernel: W_in/W_lat transpose->bf16, W_out convert, x->xb reorder
// ([b][t][k] -> chunk rows b*20+s), flags zero.  Grid 4097 x 256.
// ---------------------------------------------------------------------------
__global__ __launch_bounds__(256) void prep(
    const float* __restrict__ x, const float* __restrict__ W_in,
    const float* __restrict__ W_lat, const float* __restrict__ W_out,
    unsigned short* __restrict__ xb, unsigned short* __restrict__ WinT,
    unsigned short* __restrict__ WlatT, unsigned short* __restrict__ WoutB,
    unsigned* __restrict__ flags)
{
    __shared__ unsigned short t[64][65];
    const int blk = blockIdx.x;
    if (blk < 384) {
        const float* in; unsigned short* outp; int R, C, bx, by;
        if (blk < 128) { in = W_in;  outp = WinT;  R = 512;  C = 1024;
                         bx = (blk & 15) * 64; by = (blk >> 4) * 64; }
        else { int i = blk - 128; in = W_lat; outp = WlatT; R = 1024; C = 1024;
               bx = (i & 15) * 64; by = (i >> 4) * 64; }
        int tx = threadIdx.x & 63, ty = threadIdx.x >> 6;
        for (int r = ty; r < 64; r += 4)
            t[r][tx] = f2b(in[(size_t)(by + r) * C + bx + tx]);
        __syncthreads();
        for (int r = ty; r < 64; r += 4)
            outp[(size_t)(bx + r) * R + by + tx] = t[tx][r];
    } else if (blk < 896) {
        int i = ((blk - 384) * 256 + threadIdx.x) * 4;     // 512*1024 elems
        f32x4 v = *(const f32x4*)(W_out + i);
        ushortx4 o;
        o[0] = f2b(v[0]); o[1] = f2b(v[1]); o[2] = f2b(v[2]); o[3] = f2b(v[3]);
        *(ushortx4*)(WoutB + i) = o;
    } else if (blk < 4096) {
        size_t i8 = (size_t)((blk - 896) * 256 + threadIdx.x) * 8;
        int g = (int)(i8 >> 9), k = (int)(i8 & 511);
        int c = g / 1280, rr = g - c * 1280, b = rr / 20, s = rr - b * 20;
        const float* src = x + ((size_t)b * 200 + c * 20 + s) * 512 + k;
        f32x4 v0 = *(const f32x4*)src, v1 = *(const f32x4*)(src + 4);
        ushortx8 o;
        o[0] = f2b(v0[0]); o[1] = f2b(v0[1]); o[2] = f2b(v0[2]); o[3] = f2b(v0[3]);
        o[4] = f2b(v1[0]); o[5] = f2b(v1[1]); o[6] = f2b(v1[2]); o[7] = f2b(v1[3]);
        *(ushortx8*)(xb + i8) = o;
    } else {
        flags[threadIdx.x] = 0u;     // 256 words cover the flag region
    }
}

// ---------------------------------------------------------------------------
// Fused GLIFR kernel. 256 blocks x 256 threads, 1-2 blocks/CU.
// btile = blk&15 (4 batches, 80 rows), ntile = blk>>4 (64 hidden cols).
// Per chunk: GEMM 80x64 (K=512 xb-part, then flag-wait, K=1024 F-part),
// acc (kh-split across wave pairs) -> Csm LDS, 20-step recurrence from Csm,
// F store, release flag. After chunk 9: readout from F for this btile.
// ---------------------------------------------------------------------------
__global__ __launch_bounds__(256, 2) void fused(
    const unsigned short* __restrict__ xb,
    const unsigned short* __restrict__ WinT,
    const unsigned short* __restrict__ WlatT,
    const unsigned short* __restrict__ WoutB,
    unsigned short* __restrict__ F,
    float* __restrict__ out,
    const float* __restrict__ thresh, const float* __restrict__ t_km,
    const float* __restrict__ t_ak, const float* __restrict__ amp,
    const float* __restrict__ t_ar, const float* __restrict__ b_out,
    unsigned* __restrict__ flags)
{
    __shared__ unsigned short Asm[2 * 5120];   // 2 x (80 rows x 64) bf16
    __shared__ unsigned short Bsm[2 * 4096];   // 2 x (64 rows x 64) bf16
    __shared__ float Csm[2 * 5120];            // 2 kh-planes x (80 x 64) fp32

    const int tid  = threadIdx.x, blk = blockIdx.x;
    const int wave = tid >> 6, lane = tid & 63;
    const int m16  = lane & 15, quad = lane >> 4;
    const int kq   = (wave >> 1) * 4 + quad;   // k-slot (kh-split across waves)
    const int nh   = wave & 1;
    const int sr   = lane >> 3, sc = lane & 7;
    const int btile = blk & 15, ntile = blk >> 4;
    const int n0 = ntile * 64;
    const int r0 = btile * 80;                 // row base within a chunk

    f32x4 acc[5][2];

    auto stageA = [&](const unsigned short* src, int ld, int plane) {
#pragma unroll
        for (int g0 = 0; g0 < 12; g0 += 4) {
            int g = g0 + wave;
            if (g < 10) {
                int r = g * 8 + sr;
                gl_lds16(src + (size_t)r * ld + (sc ^ (r & 7)) * 8,
                         Asm + plane * 5120 + g * 512);
            }
        }
    };
    auto stageB = [&](const unsigned short* src, int ld, int plane) {
#pragma unroll
        for (int g0 = 0; g0 < 8; g0 += 4) {
            int g = g0 + wave;
            int r = g * 8 + sr;
            gl_lds16(src + (size_t)r * ld + (sc ^ (r & 7)) * 8,
                     Bsm + plane * 4096 + g * 512);
        }
    };
    auto compute = [&](int plane) {
        const unsigned short* Ap = Asm + plane * 5120;
        const unsigned short* Bp = Bsm + plane * 4096;
        ushortx8 a5[5], b2[2];
#pragma unroll
        for (int i = 0; i < 5; i++) {
            int ra = i * 16 + m16;
            a5[i] = *(const ushortx8*)(Ap + ra * 64 + ((kq ^ (ra & 7)) * 8));
        }
#pragma unroll
        for (int j = 0; j < 2; j++) {
            int rb = nh * 32 + j * 16 + m16;
            b2[j] = *(const ushortx8*)(Bp + rb * 64 + ((kq ^ (rb & 7)) * 8));
        }
#pragma unroll
        for (int i = 0; i < 5; i++)
#pragma unroll
            for (int j = 0; j < 2; j++)
                acc[i][j] = __builtin_amdgcn_mfma_f32_16x16x32_bf16(
                    __builtin_bit_cast(bf16x8, a5[i]),
                    __builtin_bit_cast(bf16x8, b2[j]), acc[i][j], 0, 0, 0);
    };
    // double-buffered K-loop over nk 64-wide tiles
    auto run_tiles = [&](const unsigned short* As, int lda,
                         const unsigned short* Bs, int ldb, int nk) {
        stageA(As, lda, 0);
        stageB(Bs, ldb, 0);
        __syncthreads();
        for (int kk = 0; kk < nk; kk++) {
            int cur = kk & 1;
            if (kk + 1 < nk) {
                stageA(As + (kk + 1) * 64, lda, cur ^ 1);
                stageB(Bs + (kk + 1) * 64, ldb, cur ^ 1);
            }
            compute(cur);
            __syncthreads();
        }
    };
    auto zero_acc = [&]() {
#pragma unroll
        for (int i = 0; i < 5; i++)
#pragma unroll
            for (int j = 0; j < 2; j++)
                acc[i][j] = (f32x4){0.f, 0.f, 0.f, 0.f};
    };
    auto acc_to_csm = [&]() {
        float* Cp = Csm + (wave >> 1) * 5120;
#pragma unroll
        for (int i = 0; i < 5; i++)
#pragma unroll
            for (int j = 0; j < 2; j++)
#pragma unroll
                for (int v = 0; v < 4; v++)
                    Cp[(i * 16 + quad * 4 + v) * 64 + nh * 32 + j * 16 + m16]
                        = acc[i][j][v];
    };

    // ---- GLIFR per-thread state: this block owns (btile*4+bl, n0+hl) ----
    const int bl = wave;                 // batch-local 0..3 (one per wave)
    const int hl = lane;                 // hidden-local 0..63
    const int h  = n0 + hl;
    const float th  = thresh[h];
    const float sm  = sigmoidf(t_km[h]);
    const float rm  = 0.1f * sm, om = 1.f - sm;
    const float sa0 = sigmoidf(t_ak[h]),  sa1 = sigmoidf(t_ak[1024 + h]);
    const float am0 = amp[h],             am1 = amp[1024 + h];
    const float rr0 = 1.f - 2.f * sigmoidf(t_ar[h]);
    const float rr1 = 1.f - 2.f * sigmoidf(t_ar[1024 + h]);
    float volt = 0.f, a0 = 0.f, a1 = 0.f, fir = 0.f;

    for (int c = 0; c < 10; c++) {
        zero_acc();
        // input-projection part of concat-K (no dependency)
        run_tiles(xb + (size_t)(c * 1280 + r0) * 512, 512,
                  WinT + (size_t)n0 * 512, 512, 8);
        if (c > 0) {
            // wait for F chunk c-1 of our btile (16 producer blocks)
            if (tid == 0) {
                unsigned* fl = flags + (c - 1) * 16 + btile;
                while (__hip_atomic_load(fl, __ATOMIC_RELAXED,
                                         __HIP_MEMORY_SCOPE_AGENT) < 16u)
                    __builtin_amdgcn_s_sleep(16);
                (void)__hip_atomic_load(fl, __ATOMIC_ACQUIRE,
                                        __HIP_MEMORY_SCOPE_AGENT);
            }
            __syncthreads();
            // lateral part of concat-K
            run_tiles(F + (size_t)((c - 1) * 1280 + r0) * 1024, 1024,
                      WlatT + (size_t)n0 * 1024, 1024, 16);
        }
        acc_to_csm();
        __syncthreads();
        // 20-step recurrence from LDS; F store; state in registers
#pragma unroll
        for (int s = 0; s < 20; s++) {
            float sv = Csm[(bl * 20 + s) * 64 + hl]
                     + Csm[5120 + (bl * 20 + s) * 64 + hl];
            float na0 = (am0 + rr0 * a0) * fir * sa0 + (1.f - sa0) * a0;
            float na1 = (am1 + rr1 * a1) * fir * sa1 + (1.f - sa1) * a1;
            volt = rm * (sv + na0 + na1) + om * volt;
            fir  = sigmoidf(volt - th);
            F[(size_t)(c * 1280 + r0 + bl * 20 + s) * 1024 + h] = f2b(fir);
            a0 = na0; a1 = na1;
        }
        __syncthreads();
        if (tid == 0)
            __hip_atomic_fetch_add(flags + c * 16 + btile, 1u,
                                   __ATOMIC_RELEASE, __HIP_MEMORY_SCOPE_AGENT);
    }

    // ---- readout: out rows of this btile, 5 chunks x 64 out-cols ----
    if (tid == 0) {
        unsigned* fl = flags + 9 * 16 + btile;
        while (__hip_atomic_load(fl, __ATOMIC_RELAXED,
                                 __HIP_MEMORY_SCOPE_AGENT) < 16u)
            __builtin_amdgcn_s_sleep(16);
        (void)__hip_atomic_load(fl, __ATOMIC_ACQUIRE, __HIP_MEMORY_SCOPE_AGENT);
    }
    __syncthreads();

    const int half = ntile >> 3;
    const int oc0  = (ntile & 7) * 64;
    const float bv = b_out[oc0 + hl];
    for (int cs = 0; cs < 5; cs++) {
        int cc = half * 5 + cs;
        zero_acc();
        run_tiles(F + (size_t)(cc * 1280 + r0) * 1024, 1024,
                  WoutB + (size_t)oc0 * 1024, 1024, 16);
        acc_to_csm();
        __syncthreads();
#pragma unroll
        for (int s = 0; s < 20; s++) {
            float v = Csm[(bl * 20 + s) * 64 + hl]
                    + Csm[5120 + (bl * 20 + s) * 64 + hl] + bv;
            int b = btile * 4 + bl, t = cc * 20 + s;
            out[((size_t)b * 200 + t) * 512 + oc0 + hl] = v;
        }
        __syncthreads();
    }
}

// ---------------------------------------------------------------------------
extern "C" void kernel_launch(void* const* d_in, const int* in_sizes, int n_in,
                              void* d_out, int out_size, void* d_ws, size_t ws_size,
                              hipStream_t stream)
{
    const float* x      = (const float*)d_in[0];  // [64,200,512]
    const float* W_in   = (const float*)d_in[1];  // [512,1024]
    const float* W_lat  = (const float*)d_in[2];  // [1024,1024]
    const float* thresh = (const float*)d_in[3];  // [1,1024]
    const float* t_km   = (const float*)d_in[4];  // [1,1024]
    const float* t_ak   = (const float*)d_in[5];  // [2,1,1024]
    const float* amp    = (const float*)d_in[6];  // [2,1,1024]
    const float* t_ar   = (const float*)d_in[7];  // [2,1,1024]
    const float* W_out  = (const float*)d_in[8];  // [512,1024] (n,k)
    const float* b_out  = (const float*)d_in[9];  // [512]
    float* out = (float*)d_out;                   // [64,200,512]

    char* ws = (char*)d_ws;
    unsigned short* F     = (unsigned short*)ws;
    unsigned short* xb    = (unsigned short*)(ws + 26214400);
    unsigned short* WinT  = (unsigned short*)(ws + 39321600);
    unsigned short* WlatT = (unsigned short*)(ws + 40370176);
    unsigned short* WoutB = (unsigned short*)(ws + 42467328);
    unsigned*       flags = (unsigned*)(ws + 43515904);

    prep<<<4097, 256, 0, stream>>>(x, W_in, W_lat, W_out,
                                   xb, WinT, WlatT, WoutB, flags);
    fused<<<256, 256, 0, stream>>>(xb, WinT, WlatT, WoutB, F, out,
                                   thresh, t_km, t_ak, amp, t_ar, b_out, flags);
}